// Round 1
// baseline (2109.989 us; speedup 1.0000x reference)
//
#include <hip/hip_runtime.h>
#include <math.h>

#define NB 2
#define NS 2048
#define ND 768
#define NH 12
#define DH 64
// M = NB*NS = 4096 rows for the projections

// ---------------------------------------------------------------------------
// Kernel 1: fused QKV projection.  y = x @ W^T + b  (NT gemm, K contiguous
// on both sides), scattered to [B, H, S, DH] head-major layout.
// Grid: (ND/64=12, M/64=64, 3), block 256 (16x16, 4x4 microtile).
// ---------------------------------------------------------------------------
__global__ __launch_bounds__(256) void qkv_kernel(
    const float* __restrict__ xq, const float* __restrict__ xk, const float* __restrict__ xv,
    const float* __restrict__ wq, const float* __restrict__ wk, const float* __restrict__ wv,
    const float* __restrict__ bq, const float* __restrict__ bk, const float* __restrict__ bv,
    float* __restrict__ oq, float* __restrict__ okk, float* __restrict__ ov)
{
    const int p = blockIdx.z;
    const float* x    = (p == 0) ? xq : (p == 1) ? xk : xv;
    const float* w    = (p == 0) ? wq : (p == 1) ? wk : wv;
    const float* bias = (p == 0) ? bq : (p == 1) ? bk : bv;
    float* out        = (p == 0) ? oq : (p == 1) ? okk : ov;

    const int n0 = blockIdx.x * 64;
    const int m0 = blockIdx.y * 64;
    const int tid = threadIdx.x;
    const int tx = tid & 15, ty = tid >> 4;

    __shared__ float As[16][68];   // [k][m], +4 pad keeps float4 alignment
    __shared__ float Bs[16][68];   // [k][n]

    float acc[4][4] = {};

    const int r  = tid >> 2;        // 0..63
    const int c4 = (tid & 3) << 2;  // 0,4,8,12

    for (int k0 = 0; k0 < ND; k0 += 16) {
        float4 av = *(const float4*)(x + (size_t)(m0 + r) * ND + k0 + c4);
        float4 bv4 = *(const float4*)(w + (size_t)(n0 + r) * ND + k0 + c4);
        As[c4 + 0][r] = av.x;  As[c4 + 1][r] = av.y;
        As[c4 + 2][r] = av.z;  As[c4 + 3][r] = av.w;
        Bs[c4 + 0][r] = bv4.x; Bs[c4 + 1][r] = bv4.y;
        Bs[c4 + 2][r] = bv4.z; Bs[c4 + 3][r] = bv4.w;
        __syncthreads();
#pragma unroll
        for (int kk = 0; kk < 16; ++kk) {
            float a[4], b[4];
#pragma unroll
            for (int i = 0; i < 4; ++i) a[i] = As[kk][ty * 4 + i];
#pragma unroll
            for (int j = 0; j < 4; ++j) b[j] = Bs[kk][tx * 4 + j];
#pragma unroll
            for (int i = 0; i < 4; ++i)
#pragma unroll
                for (int j = 0; j < 4; ++j) acc[i][j] += a[i] * b[j];
        }
        __syncthreads();
    }

#pragma unroll
    for (int i = 0; i < 4; ++i) {
        int m = m0 + ty * 4 + i;
        int bb = m >> 11;            // /NS
        int s  = m & (NS - 1);
#pragma unroll
        for (int j = 0; j < 4; ++j) {
            int n = n0 + tx * 4 + j;
            int h = n >> 6, dh = n & 63;
            out[(((size_t)bb * NH + h) * NS + s) * DH + dh] = acc[i][j] + bias[n];
        }
    }
}

// ---------------------------------------------------------------------------
// Kernel 2: attention.  One block = one (b,h) x 64 q-rows.
// Pass A: online (m,l) softmax stats per thread over its columns, then
//         cross-thread reduce in LDS.
// Pass B: recompute scores, write normalized probs to d_out, accumulate PV.
// k processed in 32-wide tiles; thread (tx,ty) owns score cols {tx, tx+16},
// rows ty*4..+3.  PV output dims: cols tx*4..+3.
// Grid: (NS/64=32, NB*NH=24), block 256.
// ---------------------------------------------------------------------------
__global__ __launch_bounds__(256) void attn_kernel(
    const float* __restrict__ qg, const float* __restrict__ kg, const float* __restrict__ vg,
    const int* __restrict__ mask, float* __restrict__ probs, float* __restrict__ attnout)
{
    const int bh = blockIdx.y;
    const int b = bh / NH, h = bh % NH;
    const int q0 = blockIdx.x * 64;
    const int tid = threadIdx.x;
    const int tx = tid & 15, ty = tid >> 4;

    __shared__ float Qs[64][68];
    __shared__ float Ks[32][68];
    __shared__ float Vs[32][68];
    __shared__ float Ps[64][36];
    __shared__ float red_m[64][17];
    __shared__ float red_l[64][17];
    __shared__ float row_m[64];
    __shared__ float row_linv[64];

    const size_t hb = ((size_t)b * NH + h) * NS;
    const float* qbase = qg + hb * DH;
    const float* kbase = kg + hb * DH;
    const float* vbase = vg + hb * DH;
    const int* mbase = mask + b * NS;

    // load Q tile (64 x 64) once
    for (int i = tid; i < 64 * 16; i += 256) {
        int rr = i >> 4, cc = (i & 15) << 2;
        *(float4*)&Qs[rr][cc] = *(const float4*)(qbase + (size_t)(q0 + rr) * DH + cc);
    }
    __syncthreads();

    float m_p[4], l_p[4];
#pragma unroll
    for (int i = 0; i < 4; ++i) { m_p[i] = -3.0e38f; l_p[i] = 0.0f; }

    // -------- pass A: row max + sum of exp (online) --------
    for (int kt = 0; kt < NS / 32; ++kt) {
        const int k0 = kt * 32;
        for (int i = tid; i < 32 * 16; i += 256) {
            int rr = i >> 4, cc = (i & 15) << 2;
            *(float4*)&Ks[rr][cc] = *(const float4*)(kbase + (size_t)(k0 + rr) * DH + cc);
        }
        __syncthreads();

        float sc[4][2] = {};
#pragma unroll
        for (int d = 0; d < 64; d += 4) {
            float4 kb0 = *(const float4*)&Ks[tx][d];
            float4 kb1 = *(const float4*)&Ks[tx + 16][d];
#pragma unroll
            for (int i = 0; i < 4; ++i) {
                float4 qa = *(const float4*)&Qs[ty * 4 + i][d];
                sc[i][0] += qa.x * kb0.x + qa.y * kb0.y + qa.z * kb0.z + qa.w * kb0.w;
                sc[i][1] += qa.x * kb1.x + qa.y * kb1.y + qa.z * kb1.z + qa.w * kb1.w;
            }
        }
        const int mv0 = mbase[k0 + tx];
        const int mv1 = mbase[k0 + tx + 16];
#pragma unroll
        for (int i = 0; i < 4; ++i) {
            float s0 = mv0 ? sc[i][0] * 0.125f : -1.0e9f;
            float s1 = mv1 ? sc[i][1] * 0.125f : -1.0e9f;
            float mnew = fmaxf(m_p[i], fmaxf(s0, s1));
            l_p[i] = l_p[i] * __expf(m_p[i] - mnew)
                   + __expf(s0 - mnew) + __expf(s1 - mnew);
            m_p[i] = mnew;
        }
        __syncthreads();
    }

    // -------- cross-thread reduce of (m, l) per q row --------
#pragma unroll
    for (int i = 0; i < 4; ++i) {
        red_m[ty * 4 + i][tx] = m_p[i];
        red_l[ty * 4 + i][tx] = l_p[i];
    }
    __syncthreads();
    if (tid < 64) {
        float m = -3.0e38f;
#pragma unroll
        for (int t = 0; t < 16; ++t) m = fmaxf(m, red_m[tid][t]);
        float l = 0.0f;
#pragma unroll
        for (int t = 0; t < 16; ++t) l += red_l[tid][t] * __expf(red_m[tid][t] - m);
        row_m[tid] = m;
        row_linv[tid] = 1.0f / l;
    }
    __syncthreads();

    float rm[4], rl[4];
#pragma unroll
    for (int i = 0; i < 4; ++i) {
        rm[i] = row_m[ty * 4 + i];
        rl[i] = row_linv[ty * 4 + i];
    }

    // -------- pass B: probs write + PV accumulate --------
    float o[4][4] = {};
    const size_t prow = (hb + q0) * NS;   // probs[((b*NH+h)*NS + q0)*NS]

    for (int kt = 0; kt < NS / 32; ++kt) {
        const int k0 = kt * 32;
        for (int i = tid; i < 32 * 16; i += 256) {
            int rr = i >> 4, cc = (i & 15) << 2;
            *(float4*)&Ks[rr][cc] = *(const float4*)(kbase + (size_t)(k0 + rr) * DH + cc);
            *(float4*)&Vs[rr][cc] = *(const float4*)(vbase + (size_t)(k0 + rr) * DH + cc);
        }
        __syncthreads();

        float sc[4][2] = {};
#pragma unroll
        for (int d = 0; d < 64; d += 4) {
            float4 kb0 = *(const float4*)&Ks[tx][d];
            float4 kb1 = *(const float4*)&Ks[tx + 16][d];
#pragma unroll
            for (int i = 0; i < 4; ++i) {
                float4 qa = *(const float4*)&Qs[ty * 4 + i][d];
                sc[i][0] += qa.x * kb0.x + qa.y * kb0.y + qa.z * kb0.z + qa.w * kb0.w;
                sc[i][1] += qa.x * kb1.x + qa.y * kb1.y + qa.z * kb1.z + qa.w * kb1.w;
            }
        }
        const int mv0 = mbase[k0 + tx];
        const int mv1 = mbase[k0 + tx + 16];
#pragma unroll
        for (int i = 0; i < 4; ++i) {
            int qi = ty * 4 + i;
            float s0 = mv0 ? sc[i][0] * 0.125f : -1.0e9f;
            float s1 = mv1 ? sc[i][1] * 0.125f : -1.0e9f;
            float p0 = __expf(s0 - rm[i]) * rl[i];
            float p1 = __expf(s1 - rm[i]) * rl[i];
            Ps[qi][tx]      = p0;
            Ps[qi][tx + 16] = p1;
            probs[prow + (size_t)qi * NS + k0 + tx]      = p0;
            probs[prow + (size_t)qi * NS + k0 + tx + 16] = p1;
        }
        __syncthreads();

        // O[q][d] += P[q][k] * V[k][d]
#pragma unroll
        for (int kk4 = 0; kk4 < 32; kk4 += 4) {
            float4 pa[4];
#pragma unroll
            for (int i = 0; i < 4; ++i) pa[i] = *(const float4*)&Ps[ty * 4 + i][kk4];
#pragma unroll
            for (int u = 0; u < 4; ++u) {
                float4 vr = *(const float4*)&Vs[kk4 + u][tx * 4];
#pragma unroll
                for (int i = 0; i < 4; ++i) {
                    float pv = ((const float*)&pa[i])[u];
                    o[i][0] += pv * vr.x;
                    o[i][1] += pv * vr.y;
                    o[i][2] += pv * vr.z;
                    o[i][3] += pv * vr.w;
                }
            }
        }
        __syncthreads();
    }

    // write attention output in [B, S, D] layout (head offset h*DH)
#pragma unroll
    for (int i = 0; i < 4; ++i) {
        int s = q0 + ty * 4 + i;
        float4 ov = make_float4(o[i][0], o[i][1], o[i][2], o[i][3]);
        *(float4*)(attnout + ((size_t)b * NS + s) * ND + h * DH + tx * 4) = ov;
    }
}

// ---------------------------------------------------------------------------
// Kernel 3: output projection.  out = attn @ wo^T + bo, natural [M, ND].
// Grid: (12, 64), block 256.
// ---------------------------------------------------------------------------
__global__ __launch_bounds__(256) void oproj_kernel(
    const float* __restrict__ x, const float* __restrict__ w,
    const float* __restrict__ bias, float* __restrict__ out)
{
    const int n0 = blockIdx.x * 64;
    const int m0 = blockIdx.y * 64;
    const int tid = threadIdx.x;
    const int tx = tid & 15, ty = tid >> 4;

    __shared__ float As[16][68];
    __shared__ float Bs[16][68];

    float acc[4][4] = {};

    const int r  = tid >> 2;
    const int c4 = (tid & 3) << 2;

    for (int k0 = 0; k0 < ND; k0 += 16) {
        float4 av = *(const float4*)(x + (size_t)(m0 + r) * ND + k0 + c4);
        float4 bv4 = *(const float4*)(w + (size_t)(n0 + r) * ND + k0 + c4);
        As[c4 + 0][r] = av.x;  As[c4 + 1][r] = av.y;
        As[c4 + 2][r] = av.z;  As[c4 + 3][r] = av.w;
        Bs[c4 + 0][r] = bv4.x; Bs[c4 + 1][r] = bv4.y;
        Bs[c4 + 2][r] = bv4.z; Bs[c4 + 3][r] = bv4.w;
        __syncthreads();
#pragma unroll
        for (int kk = 0; kk < 16; ++kk) {
            float a[4], b[4];
#pragma unroll
            for (int i = 0; i < 4; ++i) a[i] = As[kk][ty * 4 + i];
#pragma unroll
            for (int j = 0; j < 4; ++j) b[j] = Bs[kk][tx * 4 + j];
#pragma unroll
            for (int i = 0; i < 4; ++i)
#pragma unroll
                for (int j = 0; j < 4; ++j) acc[i][j] += a[i] * b[j];
        }
        __syncthreads();
    }

#pragma unroll
    for (int i = 0; i < 4; ++i) {
        int m = m0 + ty * 4 + i;
        float4 ov = make_float4(acc[i][0] + bias[n0 + tx * 4 + 0],
                                acc[i][1] + bias[n0 + tx * 4 + 1],
                                acc[i][2] + bias[n0 + tx * 4 + 2],
                                acc[i][3] + bias[n0 + tx * 4 + 3]);
        *(float4*)(out + (size_t)m * ND + n0 + tx * 4) = ov;
    }
}

// ---------------------------------------------------------------------------
extern "C" void kernel_launch(void* const* d_in, const int* in_sizes, int n_in,
                              void* d_out, int out_size, void* d_ws, size_t ws_size,
                              hipStream_t stream) {
    const float* query = (const float*)d_in[0];
    const float* key   = (const float*)d_in[1];
    const float* value = (const float*)d_in[2];
    const int*   amask = (const int*)d_in[3];
    const float* wq = (const float*)d_in[4];
    const float* bq = (const float*)d_in[5];
    const float* wk = (const float*)d_in[6];
    const float* bk = (const float*)d_in[7];
    const float* wv = (const float*)d_in[8];
    const float* bv = (const float*)d_in[9];
    const float* wo = (const float*)d_in[10];
    const float* bo = (const float*)d_in[11];

    const size_t elems = (size_t)NB * NS * ND;   // 3,145,728

    float* out   = (float*)d_out;                // [B,S,D]
    float* probs = out + elems;                  // [B,H,S,S]

    float* q    = (float*)d_ws;                  // [B,H,S,DH]
    float* k    = q + elems;
    float* v    = k + elems;
    float* attn = v + elems;                     // [B,S,D]

    qkv_kernel<<<dim3(ND / 64, (NB * NS) / 64, 3), 256, 0, stream>>>(
        query, key, value, wq, wk, wv, bq, bk, bv, q, k, v);

    attn_kernel<<<dim3(NS / 64, NB * NH), 256, 0, stream>>>(
        q, k, v, amask, probs, attn);

    oproj_kernel<<<dim3(ND / 64, (NB * NS) / 64), 256, 0, stream>>>(
        attn, wo, bo, out);
}

// Round 3
// 897.469 us; speedup vs baseline: 2.3510x; 2.3510x over previous
//
#include <hip/hip_runtime.h>
#include <math.h>

#define NB 2
#define NS 2048
#define ND 768
#define NH 12
#define DH 64

typedef __attribute__((ext_vector_type(8))) short short8;
typedef __attribute__((ext_vector_type(8))) __bf16 bf16x8;
typedef __attribute__((ext_vector_type(4))) float f32x4;

static __device__ inline unsigned short f2bf(float f) {
    unsigned int u = __float_as_uint(f);
    unsigned int r = (u + 0x7FFFu + ((u >> 16) & 1u)) >> 16;
    return (unsigned short)r;
}

static __device__ inline bf16x8 ld_bf8(const unsigned short* p) {
    short8 s = *(const short8*)p;
    return __builtin_bit_cast(bf16x8, s);
}

// ---------------------------------------------------------------------------
// Kernel 1: fused QKV projection, fp32 in -> bf16 out, head-major [B,H,S,DH].
// Q is pre-scaled by 0.125 (exact, pow2). 128x128 tile, 8x8 microtile.
// Grid: (ND/128=6, M/128=32, 3), block 256.
// ---------------------------------------------------------------------------
__global__ __launch_bounds__(256) void qkv_kernel(
    const float* __restrict__ xq, const float* __restrict__ xk, const float* __restrict__ xv,
    const float* __restrict__ wq, const float* __restrict__ wk, const float* __restrict__ wv,
    const float* __restrict__ bq, const float* __restrict__ bk, const float* __restrict__ bv,
    unsigned short* __restrict__ oq, unsigned short* __restrict__ okk, unsigned short* __restrict__ ov)
{
    const int p = blockIdx.z;
    const float* x    = (p == 0) ? xq : (p == 1) ? xk : xv;
    const float* w    = (p == 0) ? wq : (p == 1) ? wk : wv;
    const float* bias = (p == 0) ? bq : (p == 1) ? bk : bv;
    unsigned short* out = (p == 0) ? oq : (p == 1) ? okk : ov;
    const float qscale = (p == 0) ? 0.125f : 1.0f;

    const int n0 = blockIdx.x * 128;
    const int m0 = blockIdx.y * 128;
    const int tid = threadIdx.x;
    const int tx = tid & 15, ty = tid >> 4;

    __shared__ float As[8][132];   // [k][m]
    __shared__ float Bs[8][132];   // [k][n]

    float acc[8][8] = {};

    const int ar = tid >> 1;          // 0..127
    const int ac = (tid & 1) * 4;     // 0 or 4

    for (int k0 = 0; k0 < ND; k0 += 8) {
        float4 a = *(const float4*)(x + (size_t)(m0 + ar) * ND + k0 + ac);
        float4 b = *(const float4*)(w + (size_t)(n0 + ar) * ND + k0 + ac);
        As[ac + 0][ar] = a.x; As[ac + 1][ar] = a.y; As[ac + 2][ar] = a.z; As[ac + 3][ar] = a.w;
        Bs[ac + 0][ar] = b.x; Bs[ac + 1][ar] = b.y; Bs[ac + 2][ar] = b.z; Bs[ac + 3][ar] = b.w;
        __syncthreads();
#pragma unroll
        for (int kk = 0; kk < 8; ++kk) {
            float4 a0 = *(const float4*)&As[kk][ty * 8];
            float4 a1 = *(const float4*)&As[kk][ty * 8 + 4];
            float4 b0 = *(const float4*)&Bs[kk][tx * 8];
            float4 b1 = *(const float4*)&Bs[kk][tx * 8 + 4];
            const float av[8] = {a0.x,a0.y,a0.z,a0.w,a1.x,a1.y,a1.z,a1.w};
            const float bv8[8] = {b0.x,b0.y,b0.z,b0.w,b1.x,b1.y,b1.z,b1.w};
#pragma unroll
            for (int i = 0; i < 8; ++i)
#pragma unroll
                for (int j = 0; j < 8; ++j) acc[i][j] += av[i] * bv8[j];
        }
        __syncthreads();
    }

    const int n_base = n0 + tx * 8;
    const int h  = n_base >> 6;
    const int dh = n_base & 63;
#pragma unroll
    for (int i = 0; i < 8; ++i) {
        int m = m0 + ty * 8 + i;
        int bb = m >> 11;
        int s  = m & (NS - 1);
        unsigned short pk[8];
#pragma unroll
        for (int j = 0; j < 8; ++j) pk[j] = f2bf((acc[i][j] + bias[n_base + j]) * qscale);
        *(short8*)(out + (((size_t)bb * NH + h) * NS + s) * DH + dh) = *(short8*)pk;
    }
}

// ---------------------------------------------------------------------------
// Kernel 2: MFMA attention.  Block = (b,h) x 64 q-rows, 4 waves, each wave
// owns 16 q-rows (wave-private online softmax, no cross-wave reduction).
// Pass A: QK^T (mfma 16x16x32 bf16) -> online (m,l) via xor-shuffles.
// Pass B: recompute scores, write fp32 probs, P->bf16 LDS, PV via mfma
// (V staged transposed in LDS).
// Grid: (NS/64=32, NB*NH=24), block 256.
// ---------------------------------------------------------------------------
__global__ __launch_bounds__(256) void attn_kernel(
    const unsigned short* __restrict__ qg, const unsigned short* __restrict__ kg,
    const unsigned short* __restrict__ vg, const int* __restrict__ mask,
    float* __restrict__ probs, float* __restrict__ attnout)
{
    const int bh = blockIdx.y;
    const int b = bh / NH, h = bh % NH;
    const int q0 = blockIdx.x * 64;
    const int tid  = threadIdx.x;
    const int w    = tid >> 6;
    const int lane = tid & 63;
    const int quad = lane >> 4;
    const int c    = lane & 15;

    __shared__ unsigned short Ks[64][72];      // K rows (d contiguous), pitch 144B
    __shared__ unsigned short Vt[64][72];      // V transposed: [d][s]
    __shared__ unsigned short Ps[4][16][72];   // per-wave P (bf16), [q][k]
    __shared__ float madd[NS];                 // additive mask (0 or -1e9)

    const int* mrow = mask + b * NS;
    for (int i = tid; i < NS; i += 256) madd[i] = mrow[i] ? 0.0f : -1.0e9f;

    const size_t hb = (size_t)bh * NS;

    // A-fragments (Q, already scaled by 0.125): rows = q0 + w*16 + (lane&15)
    const unsigned short* qrow = qg + (hb + q0 + w * 16 + c) * DH;
    bf16x8 afrag0 = ld_bf8(qrow + quad * 8);
    bf16x8 afrag1 = ld_bf8(qrow + 32 + quad * 8);

    // staging indices for K (all 256 threads)
    const int krow = tid >> 2;
    const int kqtr = tid & 3;

    float m_r[4], l_r[4];
#pragma unroll
    for (int r = 0; r < 4; ++r) { m_r[r] = -3.0e38f; l_r[r] = 0.0f; }

    // ---------------- pass A ----------------
    for (int kt = 0; kt < NS / 64; ++kt) {
        const int k0 = kt * 64;
        {
            const unsigned short* src = kg + (hb + k0 + krow) * DH + kqtr * 16;
            short8 v0 = *(const short8*)src;
            short8 v1 = *(const short8*)(src + 8);
            *(short8*)&Ks[krow][kqtr * 16]     = v0;
            *(short8*)&Ks[krow][kqtr * 16 + 8] = v1;
        }
        __syncthreads();

        float sc[4][4];   // [ntile][reg]
#pragma unroll
        for (int nt = 0; nt < 4; ++nt) {
            bf16x8 b0 = ld_bf8(&Ks[nt * 16 + c][quad * 8]);
            bf16x8 b1 = ld_bf8(&Ks[nt * 16 + c][32 + quad * 8]);
            f32x4 C = {0.f, 0.f, 0.f, 0.f};
            C = __builtin_amdgcn_mfma_f32_16x16x32_bf16(afrag0, b0, C, 0, 0, 0);
            C = __builtin_amdgcn_mfma_f32_16x16x32_bf16(afrag1, b1, C, 0, 0, 0);
            const float ma = madd[k0 + nt * 16 + c];
#pragma unroll
            for (int r = 0; r < 4; ++r) sc[nt][r] = C[r] + ma;
        }
#pragma unroll
        for (int r = 0; r < 4; ++r) {
            float m = fmaxf(fmaxf(sc[0][r], sc[1][r]), fmaxf(sc[2][r], sc[3][r]));
            m = fmaxf(m, __shfl_xor(m, 1));
            m = fmaxf(m, __shfl_xor(m, 2));
            m = fmaxf(m, __shfl_xor(m, 4));
            m = fmaxf(m, __shfl_xor(m, 8));
            float mnew = fmaxf(m_r[r], m);
            float s = __expf(sc[0][r] - mnew) + __expf(sc[1][r] - mnew)
                    + __expf(sc[2][r] - mnew) + __expf(sc[3][r] - mnew);
            s += __shfl_xor(s, 1);
            s += __shfl_xor(s, 2);
            s += __shfl_xor(s, 4);
            s += __shfl_xor(s, 8);
            l_r[r] = l_r[r] * __expf(m_r[r] - mnew) + s;
            m_r[r] = mnew;
        }
        __syncthreads();
    }

    float linv[4];
#pragma unroll
    for (int r = 0; r < 4; ++r) linv[r] = 1.0f / l_r[r];

    // ---------------- pass B ----------------
    f32x4 o[4] = {{0.f,0.f,0.f,0.f},{0.f,0.f,0.f,0.f},{0.f,0.f,0.f,0.f},{0.f,0.f,0.f,0.f}};
    const size_t prow = ((size_t)bh * NS + q0 + w * 16) * NS;

    for (int kt = 0; kt < NS / 64; ++kt) {
        const int k0 = kt * 64;
        {
            const unsigned short* src = kg + (hb + k0 + krow) * DH + kqtr * 16;
            short8 v0 = *(const short8*)src;
            short8 v1 = *(const short8*)(src + 8);
            *(short8*)&Ks[krow][kqtr * 16]     = v0;
            *(short8*)&Ks[krow][kqtr * 16 + 8] = v1;
            // V transposed: wave w stages d-rows [w*16, w*16+16), s = lane
            const int d0 = w * 16;
            const unsigned short* vsrc = vg + (hb + k0 + lane) * DH + d0;
            short8 x0 = *(const short8*)vsrc;
            short8 x1 = *(const short8*)(vsrc + 8);
#pragma unroll
            for (int j = 0; j < 8; ++j) {
                Vt[d0 + j][lane]     = (unsigned short)x0[j];
                Vt[d0 + 8 + j][lane] = (unsigned short)x1[j];
            }
        }
        __syncthreads();

#pragma unroll
        for (int nt = 0; nt < 4; ++nt) {
            bf16x8 b0 = ld_bf8(&Ks[nt * 16 + c][quad * 8]);
            bf16x8 b1 = ld_bf8(&Ks[nt * 16 + c][32 + quad * 8]);
            f32x4 C = {0.f, 0.f, 0.f, 0.f};
            C = __builtin_amdgcn_mfma_f32_16x16x32_bf16(afrag0, b0, C, 0, 0, 0);
            C = __builtin_amdgcn_mfma_f32_16x16x32_bf16(afrag1, b1, C, 0, 0, 0);
            const float ma = madd[k0 + nt * 16 + c];
#pragma unroll
            for (int r = 0; r < 4; ++r) {
                float pv = __expf(C[r] + ma - m_r[r]) * linv[r];
                probs[prow + (size_t)(quad * 4 + r) * NS + k0 + nt * 16 + c] = pv;
                Ps[w][quad * 4 + r][nt * 16 + c] = f2bf(pv);
            }
        }

        // PV: A = P (wave-private, no barrier needed), B = Vt
        bf16x8 pa0 = ld_bf8(&Ps[w][c][quad * 8]);
        bf16x8 pa1 = ld_bf8(&Ps[w][c][32 + quad * 8]);
#pragma unroll
        for (int dt = 0; dt < 4; ++dt) {
            bf16x8 vb0 = ld_bf8(&Vt[dt * 16 + c][quad * 8]);
            bf16x8 vb1 = ld_bf8(&Vt[dt * 16 + c][32 + quad * 8]);
            o[dt] = __builtin_amdgcn_mfma_f32_16x16x32_bf16(pa0, vb0, o[dt], 0, 0, 0);
            o[dt] = __builtin_amdgcn_mfma_f32_16x16x32_bf16(pa1, vb1, o[dt], 0, 0, 0);
        }
        __syncthreads();
    }

    // epilogue: attn out fp32 [B,S,D]
#pragma unroll
    for (int dt = 0; dt < 4; ++dt) {
#pragma unroll
        for (int r = 0; r < 4; ++r) {
            int s = q0 + w * 16 + quad * 4 + r;
            attnout[((size_t)b * NS + s) * ND + h * DH + dt * 16 + c] = o[dt][r];
        }
    }
}

// ---------------------------------------------------------------------------
// Kernel 3: output projection, fp32.  128x128 tile, 8x8 microtile.
// Grid: (6, 32), block 256.
// ---------------------------------------------------------------------------
__global__ __launch_bounds__(256) void oproj_kernel(
    const float* __restrict__ x, const float* __restrict__ w,
    const float* __restrict__ bias, float* __restrict__ out)
{
    const int n0 = blockIdx.x * 128;
    const int m0 = blockIdx.y * 128;
    const int tid = threadIdx.x;
    const int tx = tid & 15, ty = tid >> 4;

    __shared__ float As[8][132];
    __shared__ float Bs[8][132];

    float acc[8][8] = {};

    const int ar = tid >> 1;
    const int ac = (tid & 1) * 4;

    for (int k0 = 0; k0 < ND; k0 += 8) {
        float4 a = *(const float4*)(x + (size_t)(m0 + ar) * ND + k0 + ac);
        float4 b = *(const float4*)(w + (size_t)(n0 + ar) * ND + k0 + ac);
        As[ac + 0][ar] = a.x; As[ac + 1][ar] = a.y; As[ac + 2][ar] = a.z; As[ac + 3][ar] = a.w;
        Bs[ac + 0][ar] = b.x; Bs[ac + 1][ar] = b.y; Bs[ac + 2][ar] = b.z; Bs[ac + 3][ar] = b.w;
        __syncthreads();
#pragma unroll
        for (int kk = 0; kk < 8; ++kk) {
            float4 a0 = *(const float4*)&As[kk][ty * 8];
            float4 a1 = *(const float4*)&As[kk][ty * 8 + 4];
            float4 b0 = *(const float4*)&Bs[kk][tx * 8];
            float4 b1 = *(const float4*)&Bs[kk][tx * 8 + 4];
            const float av[8] = {a0.x,a0.y,a0.z,a0.w,a1.x,a1.y,a1.z,a1.w};
            const float bv8[8] = {b0.x,b0.y,b0.z,b0.w,b1.x,b1.y,b1.z,b1.w};
#pragma unroll
            for (int i = 0; i < 8; ++i)
#pragma unroll
                for (int j = 0; j < 8; ++j) acc[i][j] += av[i] * bv8[j];
        }
        __syncthreads();
    }

#pragma unroll
    for (int i = 0; i < 8; ++i) {
        int m = m0 + ty * 8 + i;
        float4 o0 = make_float4(acc[i][0] + bias[n0 + tx * 8 + 0],
                                acc[i][1] + bias[n0 + tx * 8 + 1],
                                acc[i][2] + bias[n0 + tx * 8 + 2],
                                acc[i][3] + bias[n0 + tx * 8 + 3]);
        float4 o1 = make_float4(acc[i][4] + bias[n0 + tx * 8 + 4],
                                acc[i][5] + bias[n0 + tx * 8 + 5],
                                acc[i][6] + bias[n0 + tx * 8 + 6],
                                acc[i][7] + bias[n0 + tx * 8 + 7]);
        *(float4*)(out + (size_t)m * ND + n0 + tx * 8)     = o0;
        *(float4*)(out + (size_t)m * ND + n0 + tx * 8 + 4) = o1;
    }
}

// ---------------------------------------------------------------------------
extern "C" void kernel_launch(void* const* d_in, const int* in_sizes, int n_in,
                              void* d_out, int out_size, void* d_ws, size_t ws_size,
                              hipStream_t stream) {
    const float* query = (const float*)d_in[0];
    const float* key   = (const float*)d_in[1];
    const float* value = (const float*)d_in[2];
    const int*   amask = (const int*)d_in[3];
    const float* wq = (const float*)d_in[4];
    const float* bq = (const float*)d_in[5];
    const float* wk = (const float*)d_in[6];
    const float* bk = (const float*)d_in[7];
    const float* wv = (const float*)d_in[8];
    const float* bv = (const float*)d_in[9];
    const float* wo = (const float*)d_in[10];
    const float* bo = (const float*)d_in[11];

    const size_t elems = (size_t)NB * NS * ND;   // 3,145,728

    float* out   = (float*)d_out;                // [B,S,D]
    float* probs = out + elems;                  // [B,H,S,S]

    float* attn = (float*)d_ws;                              // [B,S,D] fp32
    unsigned short* qbf = (unsigned short*)(attn + elems);   // [B,H,S,DH] bf16 (prescaled)
    unsigned short* kbf = qbf + elems;
    unsigned short* vbf = kbf + elems;

    qkv_kernel<<<dim3(ND / 128, (NB * NS) / 128, 3), 256, 0, stream>>>(
        query, key, value, wq, wk, wv, bq, bk, bv, qbf, kbf, vbf);

    attn_kernel<<<dim3(NS / 64, NB * NH), 256, 0, stream>>>(
        qbf, kbf, vbf, amask, probs, attn);

    oproj_kernel<<<dim3(ND / 128, (NB * NS) / 128), 256, 0, stream>>>(
        attn, wo, bo, out);
}